// Round 10
// baseline (260.016 us; speedup 1.0000x reference)
//
#include <hip/hip_runtime.h>

typedef __bf16 bf16x8 __attribute__((ext_vector_type(8)));
typedef __bf16 bf16x4 __attribute__((ext_vector_type(4)));
typedef float floatx4 __attribute__((ext_vector_type(4)));

// Sizes (fixed): B=4, P=2048, DIM=1024, H=16, HKV=8, D=64
#define BSZ 4
#define SEQ 2048
#define DIM 1024
#define NH 16
#define NKV 8
#define HD 64

// Q pre-scale: D^-0.5 * log2(e), so QK^T accumulates s*log2e directly.
#define QSCALE 0.18033688011112042f
// C-init for QK^T accumulator: -10*log2(e)  ->  p = 2^(sacc) == exp(s-10)
#define CSHIFT -14.426950408889634f

#if __has_builtin(__builtin_amdgcn_exp2f)
#define EXP2(x) __builtin_amdgcn_exp2f(x)
#else
#define EXP2(x) exp2f(x)
#endif

// async global->LDS, 16B per lane; LDS dest = wave-uniform base + lane*16
#define GLDS16(g, l) __builtin_amdgcn_global_load_lds(                        \
    (const __attribute__((address_space(1))) void*)(g),                       \
    (__attribute__((address_space(3))) void*)(l), 16, 0, 0)

// ---------------------------------------------------------------------------
// Kernel 0: merged prep.
//   blocks [0,2048): x (f32) -> xb (bf16)
//   blocks [2048,2816): W transpose to bf16 [N][K]
//     Wt rows 0..1023 = Wq^T, 1024..1535 = Wk^T, 1536..2047 = Wv^T; Wpt = Wp^T
// ---------------------------------------------------------------------------
__global__ __launch_bounds__(256) void prep_kernel(
    const float* __restrict__ x,
    const float* __restrict__ Wq, const float* __restrict__ Wk,
    const float* __restrict__ Wv, const float* __restrict__ Wp,
    __bf16* __restrict__ xb, __bf16* __restrict__ Wt, __bf16* __restrict__ Wpt)
{
    __shared__ __bf16 T[64][72];   // [c][k], pad 72
    const int bid = blockIdx.x;
    const int tid = threadIdx.x;

    if (bid < 2048) {
        size_t i = ((size_t)bid * 256 + tid) * 16;
#pragma unroll
        for (int q = 0; q < 2; ++q) {
            float4 a = *(const float4*)&x[i + q * 8];
            float4 b = *(const float4*)&x[i + q * 8 + 4];
            bf16x8 o;
            o[0] = (__bf16)a.x; o[1] = (__bf16)a.y; o[2] = (__bf16)a.z; o[3] = (__bf16)a.w;
            o[4] = (__bf16)b.x; o[5] = (__bf16)b.y; o[6] = (__bf16)b.z; o[7] = (__bf16)b.w;
            *(bf16x8*)&xb[i + q * 8] = o;
        }
        return;
    }

    const int t  = bid - 2048;
    const int k0 = (t & 15) * 64;
    const int cg = (t >> 4) * 64;

    const float* W; int ldn, cl, orow; __bf16* out;
    if (cg < 1024)      { W = Wq; ldn = 1024; cl = cg;        out = Wt;  orow = cg; }
    else if (cg < 1536) { W = Wk; ldn = 512;  cl = cg - 1024; out = Wt;  orow = cg; }
    else if (cg < 2048) { W = Wv; ldn = 512;  cl = cg - 1536; out = Wt;  orow = cg; }
    else                { W = Wp; ldn = 1024; cl = cg - 2048; out = Wpt; orow = cg - 2048; }

    const int kr = tid >> 2;            // tile row (k), 0..63
    const int cq = (tid & 3) * 16;      // tile col base (c)
#pragma unroll
    for (int j = 0; j < 4; ++j) {
        float4 f = *(const float4*)&W[(size_t)(k0 + kr) * ldn + cl + cq + j * 4];
        T[cq + j * 4 + 0][kr] = (__bf16)f.x;
        T[cq + j * 4 + 1][kr] = (__bf16)f.y;
        T[cq + j * 4 + 2][kr] = (__bf16)f.z;
        T[cq + j * 4 + 3][kr] = (__bf16)f.w;
    }
    __syncthreads();
#pragma unroll
    for (int j = 0; j < 2; ++j) {
        int ch = tid * 2 + j;                 // 512 chunks of 16B
        int c = ch >> 3, kc = (ch & 7) * 8;
        *(bf16x8*)&out[(size_t)(orow + c) * 1024 + k0 + kc] = *(bf16x8*)&T[c][kc];
    }
}

// ---------------------------------------------------------------------------
// Kernel 1: fused QKV projection, 128x128 tile, BK=32, 2-phase dbuf.
// XCD-chunked bijective block swizzle (kept from r9: measured win, FETCH
// evidence).  V-region epilogue transposes through LDS (v8).
// ---------------------------------------------------------------------------
#define QSTAGE(bi, kk)                                                        \
    {                                                                         \
        GLDS16(Ag + (kk),             Asb + (bi) * 4096 + wv * 512);          \
        GLDS16(Ag + (kk) + 64 * 1024, Asb + (bi) * 4096 + 2048 + wv * 512);   \
        GLDS16(Bg + (kk),             Bsb + (bi) * 4096 + wv * 512);          \
        GLDS16(Bg + (kk) + 64 * 1024, Bsb + (bi) * 4096 + 2048 + wv * 512);   \
    }

__global__ __launch_bounds__(256) void qkv_gemm(
    const __bf16* __restrict__ xb, const __bf16* __restrict__ Wt,
    __bf16* __restrict__ qw, __bf16* __restrict__ kw, __bf16* __restrict__ vw)
{
    extern __shared__ __align__(16) __bf16 smem[];   // 34816 B
    __bf16* Asb = smem;            // As[bi] = Asb + bi*4096   (16 KB)
    __bf16* Bsb = smem + 8192;     // Bs[bi] = Bsb + bi*4096   (16 KB)

    // XCD-chunked swizzle: id%8 == XCD (round-robin); give XCD c the
    // contiguous newid range [c*128,(c+1)*128) = 8 m-panels x all 16 c-blocks.
    const int id  = blockIdx.x + (blockIdx.y << 4);      // gridDim=(16,64)
    const int nid = (id & 7) * 128 + (id >> 3);
    const int m0 = (nid >> 4) * 128;
    const int c0 = (nid & 15) * 128;

    const int tid  = threadIdx.x;
    const int lane = tid & 63, wv = tid >> 6;
    const int l16  = lane & 15, quad = lane >> 4;
    const int wr = (wv >> 1) * 64, wc = (wv & 1) * 64;

    const int srow = wv * 16 + (lane >> 2);
    const int skc  = (lane & 3) * 8;
    const __bf16* Ag = xb + (size_t)(m0 + srow) * 1024 + skc;
    const __bf16* Bg = Wt + (size_t)(c0 + srow) * 1024 + skc;

    floatx4 acc[4][4] = {};

    QSTAGE(0, 0);
    __syncthreads();

    for (int t = 0; t < 32; ++t) {
        const int cur = t & 1;
        if (t < 31) QSTAGE(cur ^ 1, (t + 1) * 32);

        bf16x8 af[4], bfr[4];
#pragma unroll
        for (int tt = 0; tt < 4; ++tt) {
            af[tt]  = *(bf16x8*)&Asb[cur * 4096 + (wr + tt * 16 + l16) * 32 + quad * 8];
            bfr[tt] = *(bf16x8*)&Bsb[cur * 4096 + (wc + tt * 16 + l16) * 32 + quad * 8];
        }
#pragma unroll
        for (int mt = 0; mt < 4; ++mt)
#pragma unroll
            for (int nt = 0; nt < 4; ++nt)
                acc[mt][nt] = __builtin_amdgcn_mfma_f32_16x16x32_bf16(
                    af[mt], bfr[nt], acc[mt][nt], 0, 0, 0);
        __syncthreads();
    }

    const int bb = m0 >> 11;          // regions are block-uniform
    if (c0 < 1536) {
        // Q / K regions: stores along d are coalesced (lane = d)
#pragma unroll
        for (int mt = 0; mt < 4; ++mt) {
#pragma unroll
            for (int nt = 0; nt < 4; ++nt) {
#pragma unroll
                for (int r = 0; r < 4; ++r) {
                    int m = m0 + wr + mt * 16 + quad * 4 + r;
                    int c = c0 + wc + nt * 16 + l16;
                    int p = m & 2047;
                    float val = acc[mt][nt][r];
                    if (c < 1024) {
                        int h = c >> 6, d = c & 63;
                        qw[(((size_t)bb * NH + h) * SEQ + p) * HD + d] = (__bf16)(val * QSCALE);
                    } else {
                        int cc = c - 1024, hh = cc >> 6, d = cc & 63;
                        kw[(((size_t)bb * NKV + hh) * SEQ + p) * HD + d] = (__bf16)val;
                    }
                }
            }
        }
    } else {
        // V region: transpose through LDS, then coalesced stores along p.
        __bf16* T = smem;   // [c_local][m_local], row stride 136
#pragma unroll
        for (int mt = 0; mt < 4; ++mt)
#pragma unroll
            for (int nt = 0; nt < 4; ++nt) {
                bf16x4 pv;
#pragma unroll
                for (int r = 0; r < 4; ++r) pv[r] = (__bf16)acc[mt][nt][r];
                *(bf16x4*)&T[(wc + nt * 16 + l16) * 136 + wr + mt * 16 + quad * 4] = pv;
            }
        __syncthreads();

        const int c_l = tid >> 1, half = tid & 1;
        const int cc = c0 - 1536 + c_l, hh = cc >> 6, d = cc & 63;
        const int p0 = (m0 & 2047) + half * 64;
        __bf16* dst = &vw[((size_t)(bb * NKV + hh) * HD + d) * SEQ + p0];
        const __bf16* src = &T[c_l * 136 + half * 64];
#pragma unroll
        for (int i = 0; i < 8; ++i)
            *(bf16x8*)&dst[i * 8] = *(const bf16x8*)&src[i * 8];
    }
}

// ---------------------------------------------------------------------------
// Kernel 2: partial sum-of-squares of k. 256 blocks: (b*8+kv)*8 + slice.
// ---------------------------------------------------------------------------
__global__ __launch_bounds__(256) void ksumsq(const __bf16* __restrict__ kw,
                                              float* __restrict__ partial)
{
    const int blk = blockIdx.x;
    const __bf16* base = kw + (size_t)(blk >> 3) * (SEQ * HD)
                            + (size_t)(blk & 7) * (SEQ * HD / 8);
    const int tid = threadIdx.x;

    float s = 0.f;
#pragma unroll
    for (int i = tid * 8; i < SEQ * HD / 8; i += 256 * 8) {
        bf16x8 vv = *(const bf16x8*)&base[i];
#pragma unroll
        for (int j = 0; j < 8; ++j) { float f = (float)vv[j]; s += f * f; }
    }
#pragma unroll
    for (int off = 1; off < 64; off <<= 1) s += __shfl_xor(s, off, 64);

    __shared__ float red[4];
    if ((tid & 63) == 0) red[tid >> 6] = s;
    __syncthreads();
    if (tid == 0) partial[blk] = red[0] + red[1] + red[2] + red[3];
}

// ---------------------------------------------------------------------------
// Kernel 3: ratios + kv_id (replica of _ratios + searchsorted-right)
// ---------------------------------------------------------------------------
__global__ void ratios_kernel(const float* __restrict__ partial,
                              const float* __restrict__ cache,
                              int* __restrict__ kv_id)
{
    if (threadIdx.x != 0 || blockIdx.x != 0) return;
    float mag[8] = {0.f, 0.f, 0.f, 0.f, 0.f, 0.f, 0.f, 0.f};
    for (int b = 0; b < 4; ++b)
        for (int j = 0; j < 8; ++j) {
            float ss = 0.f;
            for (int sl = 0; sl < 8; ++sl) ss += partial[(b * 8 + j) * 8 + sl];
            mag[j] += sqrtf(ss);
        }
    float diff[8], sum = 0.f;
    for (int j = 0; j < 8; ++j) {
        diff[j] = fabsf(cache[j] - mag[j]);
        sum += diff[j];
    }
    int r[8], s = 0;
    for (int j = 0; j < 8; ++j) {
        r[j] = (int)rintf(diff[j] / sum * 16.0f);  // round half to even (jnp.round)
        s += r[j];
    }
    while (s > 16) {
        int jm = 0;
        for (int j = 1; j < 8; ++j) if (r[j] > r[jm]) jm = j;
        r[jm]--; s--;
    }
    while (s < 16) {
        int jm = 0;
        for (int j = 1; j < 8; ++j) if (r[j] < r[jm]) jm = j;
        r[jm]++; s++;
    }
    int cum[8], c = 0;
    for (int j = 0; j < 8; ++j) { c += r[j]; cum[j] = c; }
    for (int h = 0; h < 16; ++h) {
        int j = 0;
        while (j < 7 && cum[j] <= h) j++;  // searchsorted side='right'
        kv_id[h] = j;
    }
}

// ---------------------------------------------------------------------------
// Kernel 4: flash attention — round-8 verified version, verbatim (natural
// block mapping; r9's XCD swizzle on attn REVERTED per m160 L3-fit evidence
// + measured -4.7us regression).  exp2 softmax via Q*log2e + C-init;
// denominator via ones-B MFMA row-sum; 4 q-sets/wave; P in registers with
// matching-key-permutation PV; double-buffered K/V; one barrier per K-tile.
// ---------------------------------------------------------------------------
__global__ __launch_bounds__(256, 2) void attn_kernel(
    const __bf16* __restrict__ qw, const __bf16* __restrict__ kw,
    const __bf16* __restrict__ vw, const int* __restrict__ kv_id,
    __bf16* __restrict__ attn_out)
{
    __shared__ __align__(16) __bf16 Kt[2][64 * 72];    // [key][d], pad 72
    __shared__ __align__(16) __bf16 VT[2][64 * 72];    // [d][key], pad 72

    const int bh = blockIdx.y;           // 0..63
    const int b = bh >> 4, h = bh & 15;
    const int q0 = blockIdx.x * 256;
    const int kv = kv_id[h];

    const __bf16* Kg = kw + ((size_t)(b * NKV + kv) * SEQ) * HD;    // [p][d]
    const __bf16* Vg = vw + ((size_t)(b * NKV + kv) * HD) * SEQ;    // [d][p]
    const __bf16* Qg = qw + ((size_t)(b * NH + h) * SEQ + q0) * HD;

    const int tid  = threadIdx.x;
    const int lane = tid & 63, wv = tid >> 6;
    const int l16  = lane & 15, quad = lane >> 4;

    // Four independent Q fragment sets: qrow = 64*wv + 16*s + l16
    bf16x8 qf[4][2];
#pragma unroll
    for (int s = 0; s < 4; ++s) {
        const __bf16* qp = &Qg[(size_t)(64 * wv + 16 * s + l16) * HD];
        qf[s][0] = *(const bf16x8*)&qp[quad * 8];
        qf[s][1] = *(const bf16x8*)&qp[32 + quad * 8];
    }

    bf16x8 vones;
#pragma unroll
    for (int j = 0; j < 8; ++j) vones[j] = (__bf16)1.0f;

    floatx4 o[4][4] = {};
    floatx4 ol[4] = {};     // denominators via MFMA row-sum

    // staging geometry: thread covers (row = tid>>2, 32B chunk = (tid&3)*16)
    const int row = tid >> 2, cc = (tid & 3) << 4;
    const __bf16* kp = Kg + (size_t)row * HD + cc;    // +4096/tile
    const __bf16* vp = Vg + (size_t)row * SEQ + cc;   // +64/tile

    // prologue: tile 0 -> buf 0
    bf16x8 rk0 = *(const bf16x8*)kp;
    bf16x8 rk1 = *(const bf16x8*)(kp + 8);
    bf16x8 rv0 = *(const bf16x8*)vp;
    bf16x8 rv1 = *(const bf16x8*)(vp + 8);
    {
        __bf16* kd = &Kt[0][row * 72 + cc];
        *(bf16x8*)kd = rk0; *(bf16x8*)(kd + 8) = rk1;
        __bf16* vd = &VT[0][row * 72 + cc];
        *(bf16x8*)vd = rv0; *(bf16x8*)(vd + 8) = rv1;
    }
    __syncthreads();

    const floatx4 cinit = {CSHIFT, CSHIFT, CSHIFT, CSHIFT};

    for (int kb = 0; kb < 32; ++kb) {
        const int cur = kb & 1;
        const __bf16* Kc = &Kt[cur][0];
        const __bf16* Vc = &VT[cur][0];

        // ---- QK^T: S^T[key][q] * log2e - 10*log2e, C-initialized ----------
        floatx4 sacc[4][4];
#pragma unroll
        for (int s = 0; s < 4; ++s)
#pragma unroll
            for (int t = 0; t < 4; ++t) sacc[s][t] = cinit;
        {
            bf16x8 kf[4];
#pragma unroll
            for (int t = 0; t < 4; ++t)
                kf[t] = *(bf16x8*)&Kc[(16 * t + l16) * 72 + quad * 8];
#pragma unroll
            for (int t = 0; t < 4; ++t)
#pragma unroll
                for (int s = 0; s < 4; ++s)
                    sacc[s][t] = __builtin_amdgcn_mfma_f32_16x16x32_bf16(
                        kf[t], qf[s][0], sacc[s][t], 0, 0, 0);
#pragma unroll
            for (int t = 0; t < 4; ++t)
                kf[t] = *(bf16x8*)&Kc[(16 * t + l16) * 72 + 32 + quad * 8];
#pragma unroll
            for (int t = 0; t < 4; ++t)
#pragma unroll
                for (int s = 0; s < 4; ++s)
                    sacc[s][t] = __builtin_amdgcn_mfma_f32_16x16x32_bf16(
                        kf[t], qf[s][1], sacc[s][t], 0, 0, 0);
        }

        // ---- prefetch next K/V tile into registers (hides under softmax+PV)
        if (kb < 31) {
            const __bf16* kn = kp + (size_t)(kb + 1) * (64 * HD);
            const __bf16* vn = vp + (kb + 1) * 64;
            rk0 = *(const bf16x8*)kn;
            rk1 = *(const bf16x8*)(kn + 8);
            rv0 = *(const bf16x8*)vn;
            rv1 = *(const bf16x8*)(vn + 8);
        }

        // ---- softmax: p = 2^sacc, one v_exp per score ----------------------
        bf16x8 a0s[4], a1s[4];
#pragma unroll
        for (int s = 0; s < 4; ++s) {
            bf16x8 a0, a1;
#pragma unroll
            for (int r = 0; r < 4; ++r) {
                float e0 = EXP2(sacc[s][0][r]);
                float e1 = EXP2(sacc[s][1][r]);
                float e2 = EXP2(sacc[s][2][r]);
                float e3 = EXP2(sacc[s][3][r]);
                a0[r] = (__bf16)e0; a0[4 + r] = (__bf16)e1;
                a1[r] = (__bf16)e2; a1[4 + r] = (__bf16)e3;
            }
            a0s[s] = a0; a1s[s] = a1;
        }

        // ---- denominators: ol[s] += rowsum(P) via ones-B MFMA --------------
#pragma unroll
        for (int s = 0; s < 4; ++s) {
            ol[s] = __builtin_amdgcn_mfma_f32_16x16x32_bf16(a0s[s], vones, ol[s], 0, 0, 0);
            ol[s] = __builtin_amdgcn_mfma_f32_16x16x32_bf16(a1s[s], vones, ol[s], 0, 0, 0);
        }

        // ---- O += P V; B-operand read with matching key permutation,
        //      V fragments read ONCE and reused by all four sets -------------
#pragma unroll
        for (int dt = 0; dt < 4; ++dt) {
            const __bf16* vrow = &Vc[(16 * dt + l16) * 72 + 4 * quad];
            bf16x4 lo0 = *(const bf16x4*)vrow;          // keys  4q..+3
            bf16x4 hi0 = *(const bf16x4*)(vrow + 16);   // keys 16+4q..+3
            bf16x8 vb0 = __builtin_shufflevector(lo0, hi0, 0, 1, 2, 3, 4, 5, 6, 7);
#pragma unroll
            for (int s = 0; s < 4; ++s)
                o[s][dt] = __builtin_amdgcn_mfma_f32_16x16x32_bf16(
                    a0s[s], vb0, o[s][dt], 0, 0, 0);
            bf16x4 lo1 = *(const bf16x4*)(vrow + 32);   // keys 32+4q..+3
            bf16x4 hi1 = *(const bf16x4*)(vrow + 48);   // keys 48+4q..+3
            bf16x8 vb1 = __builtin_shufflevector(lo1, hi1, 0, 1, 2, 3, 4, 5, 6, 7);
#pragma unroll
            for (int s = 0; s < 4; ++s)
                o[s][dt] = __builtin_amdgcn_mfma_f32_16x16x32_bf16(
                    a1s[s], vb1, o[s][dt], 0, 0, 0);
        }

        // ---- write prefetched tile to the other buffer, single barrier ----
        if (kb < 31) {
            __bf16* kd = &Kt[cur ^ 1][row * 72 + cc];
            *(bf16x8*)kd = rk0; *(bf16x8*)(kd + 8) = rk1;
            __bf16* vd = &VT[cur ^ 1][row * 72 + cc];
            *(bf16x8*)vd = rv0; *(bf16x8*)(vd + 8) = rv1;
        }
        __syncthreads();
    }

    // epilogue per set: denom from ol (same C row mapping as o), store
#pragma unroll
    for (int s = 0; s < 4; ++s) {
#pragma unroll
        for (int r = 0; r < 4; ++r) {
            float inv = 1.f / ol[s][r];
            int p_ = q0 + 64 * wv + 16 * s + quad * 4 + r;
#pragma unroll
            for (int dt = 0; dt < 4; ++dt) {
                int d = 16 * dt + l16;
                attn_out[(((size_t)b * SEQ + p_) * NH + h) * HD + d] = (__bf16)(o[s][dt][r] * inv);
            }
        }
    }
}

// ---------------------------------------------------------------------------
// Kernel 5: output projection, 128x128 tile, BK=32, 2-phase dbuf.
// XCD-chunked swizzle kept (r9).
// ---------------------------------------------------------------------------
#define GSTAGE(bi, kk)                                                        \
    {                                                                         \
        GLDS16(Ag + (kk),             &As[bi][wv * 512]);                     \
        GLDS16(Ag + (kk) + 64 * 1024, &As[bi][2048 + wv * 512]);              \
        GLDS16(Bg + (kk),             &Bs[bi][wv * 512]);                     \
        GLDS16(Bg + (kk) + 64 * 1024, &Bs[bi][2048 + wv * 512]);              \
    }

__global__ __launch_bounds__(256) void proj_gemm(
    const __bf16* __restrict__ A, const __bf16* __restrict__ Wpt,
    const float* __restrict__ bp, float* __restrict__ out)
{
    __shared__ __align__(16) __bf16 As[2][128 * 32];
    __shared__ __align__(16) __bf16 Bs[2][128 * 32];

    const int id  = blockIdx.x + (blockIdx.y << 3);      // gridDim=(8,64)
    const int nid = (id & 7) * 64 + (id >> 3);
    const int m0 = (nid >> 3) * 128, c0 = (nid & 7) * 128;

    const int tid = threadIdx.x, lane = tid & 63, wv = tid >> 6;
    const int l16 = lane & 15, quad = lane >> 4;
    const int wr = (wv >> 1) * 64, wc = (wv & 1) * 64;

    const int srow = wv * 16 + (lane >> 2);
    const int skc  = (lane & 3) * 8;
    const __bf16* Ag = A   + (size_t)(m0 + srow) * 1024 + skc;
    const __bf16* Bg = Wpt + (size_t)(c0 + srow) * 1024 + skc;

    floatx4 acc[4][4] = {};

    GSTAGE(0, 0);
    __syncthreads();

    for (int t = 0; t < 32; ++t) {
        const int cur = t & 1;
        if (t < 31) GSTAGE(cur ^ 1, (t + 1) * 32);

        bf16x8 af[4], bfr[4];
#pragma unroll
        for (int tt = 0; tt < 4; ++tt) {
            af[tt]  = *(bf16x8*)&As[cur][(wr + tt * 16 + l16) * 32 + quad * 8];
            bfr[tt] = *(bf16x8*)&Bs[cur][(wc + tt * 16 + l16) * 32 + quad * 8];
        }
#pragma unroll
        for (int mt = 0; mt < 4; ++mt)
#pragma unroll
            for (int nt = 0; nt < 4; ++nt)
                acc[mt][nt] = __builtin_amdgcn_mfma_f32_16x16x32_bf16(
                    af[mt], bfr[nt], acc[mt][nt], 0, 0, 0);
        __syncthreads();
    }

#pragma unroll
    for (int nt = 0; nt < 4; ++nt) {
        int c = c0 + wc + nt * 16 + l16;
        float bias = bp[c];
#pragma unroll
        for (int mt = 0; mt < 4; ++mt)
#pragma unroll
            for (int r = 0; r < 4; ++r) {
                int m = m0 + wr + mt * 16 + quad * 4 + r;
                out[(size_t)m * 1024 + c] = acc[mt][nt][r] + bias;
            }
    }
}

// ---------------------------------------------------------------------------
extern "C" void kernel_launch(void* const* d_in, const int* in_sizes, int n_in,
                              void* d_out, int out_size, void* d_ws, size_t ws_size,
                              hipStream_t stream)
{
    const float* x     = (const float*)d_in[0];
    const float* Wq    = (const float*)d_in[1];
    const float* Wk    = (const float*)d_in[2];
    const float* Wv    = (const float*)d_in[3];
    const float* Wp    = (const float*)d_in[4];
    const float* bp    = (const float*)d_in[5];
    const float* cache = (const float*)d_in[6];
    float* outp = (float*)d_out;

    __bf16* ws = (__bf16*)d_ws;
    __bf16* qw  = ws;                                    // [B][H][P][D]      16 MB
    __bf16* kw  = qw + (size_t)BSZ * NH * SEQ * HD;      // [B][HKV][P][D]     8 MB
    __bf16* vw  = kw + (size_t)BSZ * NKV * SEQ * HD;     // [B][HKV][D][P]     8 MB
    __bf16* at  = vw + (size_t)BSZ * NKV * SEQ * HD;     // [B][P][H*D]       16 MB
    __bf16* xb  = at + (size_t)BSZ * NH * SEQ * HD;      // x in bf16         16 MB
    __bf16* Wt  = xb + (size_t)BSZ * SEQ * DIM;          // [Wq|Wk|Wv]^T bf16  4 MB
    __bf16* Wpt = Wt + (size_t)2048 * 1024;              // Wp^T bf16          2 MB
    float* partial = (float*)(Wpt + (size_t)1024 * 1024);  // 256 floats
    int*   kv_id   = (int*)(partial + 256);                // 16 ints

    prep_kernel<<<2816, 256, 0, stream>>>(x, Wq, Wk, Wv, Wp, xb, Wt, Wpt);
    qkv_gemm<<<dim3(16, 64), 256, 34816, stream>>>(xb, Wt, qw, kw, vw);
    ksumsq<<<256, 256, 0, stream>>>(kw, partial);
    ratios_kernel<<<1, 64, 0, stream>>>(partial, cache, kv_id);
    attn_kernel<<<dim3(8, 64), 256, 0, stream>>>(qw, kw, vw, kv_id, at);
    proj_gemm<<<dim3(8, 64), 256, 0, stream>>>(at, Wpt, bp, outp);
}